// Round 19
// baseline (125.066 us; speedup 1.0000x reference)
//
#include <hip/hip_runtime.h>

typedef __fp16   cvt16x2 __attribute__((ext_vector_type(2)));
typedef _Float16 h2      __attribute__((ext_vector_type(2)));
typedef _Float16 half4_t __attribute__((ext_vector_type(4)));
typedef unsigned uint2v  __attribute__((ext_vector_type(2)));
typedef float    f32x4   __attribute__((ext_vector_type(4)));
typedef float    f32x4u  __attribute__((ext_vector_type(4), aligned(4)));

#define NSB 32          // sub-batches (16 samples each) per wave => 512/wave
#define LOG2E 1.44269504f
#define LN2   0.69314718f

#if !__has_builtin(__builtin_elementwise_exp2)
extern "C" __device__ _Float16 __ocml_exp2_f16(_Float16);
#endif

__device__ __forceinline__ unsigned pk(float a, float b) {
    cvt16x2 h = __builtin_amdgcn_cvt_pkrtz(a, b);
    return __builtin_bit_cast(unsigned, h);
}
__device__ __forceinline__ half4_t mkfrag(unsigned lo, unsigned hi) {
    uint2v u; u[0] = lo; u[1] = hi;
    return __builtin_bit_cast(half4_t, u);
}

// Scaled-domain ELU (hardware v_exp_f16).
__device__ __forceinline__ unsigned elu_pk(float a, float b) {
    h2 v = __builtin_bit_cast(h2, __builtin_amdgcn_cvt_pkrtz(a, b));
    const h2 z   = {(_Float16)0.f, (_Float16)0.f};
    const h2 lg  = {(_Float16)LOG2E, (_Float16)LOG2E};
    const h2 mlg = {(_Float16)(-LOG2E), (_Float16)(-LOG2E)};
    h2 t = __builtin_elementwise_min(v, z);
#if __has_builtin(__builtin_elementwise_exp2)
    h2 ev = __builtin_elementwise_exp2(t);
#else
    h2 ev; ev[0] = __ocml_exp2_f16(t[0]); ev[1] = __ocml_exp2_f16(t[1]);
#endif
    h2 r = __builtin_elementwise_max(v, ev * lg + mlg);
    return __builtin_bit_cast(unsigned, r);
}

// TLP variant (R17 fixed): ONE sub-batch in flight per wave, minimal VGPR,
// __launch_bounds__(128,8) -> target 8 waves/SIMD. Addressing audit:
//   wave covers samples [bid*1024 + w*512, +512), sub-batch it covers
//   [wavebase + it*16, +16), lane m handles sample wavebase + it*16 + m.
__global__ __launch_bounds__(128, 8) void pixenc_mfma17(
    const float* __restrict__ x,
    const float* __restrict__ Bl,
    const float* __restrict__ W1, const float* __restrict__ b1,
    const float* __restrict__ W2, const float* __restrict__ b2,
    const float* __restrict__ W3, const float* __restrict__ b3,
    const float* __restrict__ W4, const float* __restrict__ b4,
    const float* __restrict__ W5, const float* __restrict__ b5,
    float* __restrict__ out)
{
    const int t    = threadIdx.x;
    const int lane = t & 63;
    const int w    = t >> 6;
    const int g    = lane >> 4;
    const int m    = lane & 15;

    const int coff = (g == 0) ? 7 : (g == 2) ? 3 : 0;   // 16B window start

    half4_t A1[3], A2, A3, A4;
    #pragma unroll
    for (int e = 0; e < 4; ++e) {
        const bool valid = (g == 1) | (g == 0 && e < 2) | (g == 2 && e >= 1);
        A1[0][e] = valid ? (_Float16)(W1[(coff + e) * 16 + m] * LOG2E)
                         : (_Float16)0.f;
        A1[1][e] = (_Float16)(W1[(9  + g * 4 + e) * 16 + m] * LOG2E);
        A1[2][e] = (_Float16)(W1[(25 + g * 4 + e) * 16 + m] * LOG2E);
        A2[e]    = (_Float16)W2[(g * 4 + e) * 16 + m];
        A3[e]    = (_Float16)W3[(g * 4 + e) * 16 + m];
        A4[e]    = (_Float16)W4[(g * 4 + e) * 16 + m];
    }
    const half4_t Az = (g == 0) ? mkfrag(pk(Bl[m], Bl[16 + m]), 0u)
                                : mkfrag(0u, 0u);
    const half4_t A5 = (m == 0)
        ? mkfrag(pk(W5[g * 4 + 0] * LN2, W5[g * 4 + 1] * LN2),
                 pk(W5[g * 4 + 2] * LN2, W5[g * 4 + 3] * LN2))
        : mkfrag(0u, 0u);
    f32x4 c1, c2, c3, c4;
    #pragma unroll
    for (int e = 0; e < 4; ++e) {
        const int r = g * 4 + e;
        c1[e] = b1[r] * LOG2E; c2[e] = b2[r] * LOG2E;
        c3[e] = b3[r] * LOG2E; c4[e] = b4[r] * LOG2E;
    }
    const f32x4 zero4 = {0.f, 0.f, 0.f, 0.f};
    const float b5v = b5[0];                     // uniform -> SGPR

    // samples: block covers 32*NSB = 1024; wave covers 16*NSB = 512
    const int wavebase = blockIdx.x * (32 * NSB) + w * (16 * NSB);
    const float* aP = x + (size_t)(wavebase + m) * 11 + coff;
    float* outp = out + wavebase + m;

    // ---- prologue: load sub-batch 0 ----
    unsigned cp01, cp23;
    {
        const f32x4u v = *(const f32x4u*)aP;
        cp01 = pk(v[0], v[1]);
        cp23 = pk(v[2], v[3]);
    }

    #pragma unroll 2
    for (int it = 0; it < NSB; ++it) {
        // ---- prefetch next sub-batch ----
        unsigned np01, np23;
        if (it + 1 < NSB) {
            const f32x4u v = *(const f32x4u*)(aP + 176);
            np01 = pk(v[0], v[1]);
            np23 = pk(v[2], v[3]);
        }
        aP += 176;                                // 16 samples * 11 floats

        // ---- front: z-MFMA -> sincos -> L1 (3 MFMAs) ----
        const f32x4 az = __builtin_amdgcn_mfma_f32_16x16x16f16(
                             Az, mkfrag(cp23, 0u), zero4, 0, 0, 0);
        float cs[4], sn[4];
        #pragma unroll
        for (int e = 0; e < 4; ++e) {
            cs[e] = __builtin_amdgcn_cosf(az[e]);
            sn[e] = __builtin_amdgcn_sinf(az[e]);
        }
        const half4_t F0 = mkfrag(cp01, cp23);
        const half4_t F1 = mkfrag(pk(cs[0], cs[1]), pk(cs[2], cs[3]));
        const half4_t F2 = mkfrag(pk(sn[0], sn[1]), pk(sn[2], sn[3]));
        f32x4 a = __builtin_amdgcn_mfma_f32_16x16x16f16(A1[0], F0, c1, 0, 0, 0);
        a = __builtin_amdgcn_mfma_f32_16x16x16f16(A1[1], F1, a, 0, 0, 0);
        a = __builtin_amdgcn_mfma_f32_16x16x16f16(A1[2], F2, a, 0, 0, 0);

        // ---- back: 3x(ELU+MFMA) + ELU + head-MFMA + store ----
        a = __builtin_amdgcn_mfma_f32_16x16x16f16(
                A2, mkfrag(elu_pk(a[0], a[1]), elu_pk(a[2], a[3])), c2, 0, 0, 0);
        a = __builtin_amdgcn_mfma_f32_16x16x16f16(
                A3, mkfrag(elu_pk(a[0], a[1]), elu_pk(a[2], a[3])), c3, 0, 0, 0);
        a = __builtin_amdgcn_mfma_f32_16x16x16f16(
                A4, mkfrag(elu_pk(a[0], a[1]), elu_pk(a[2], a[3])), c4, 0, 0, 0);
        const f32x4 oh = __builtin_amdgcn_mfma_f32_16x16x16f16(
                A5, mkfrag(elu_pk(a[0], a[1]), elu_pk(a[2], a[3])), zero4, 0, 0, 0);
        if (g == 0) outp[it * 16] = oh[0] + b5v;

        // ---- rotate prefetch ----
        if (it + 1 < NSB) { cp01 = np01; cp23 = np23; }
    }
}

// Guarded scalar tail (only launched when N % 1024 != 0; never for N=8388608).
__global__ void pixenc_tail(
    const float* __restrict__ x, const float* __restrict__ Bl,
    const float* __restrict__ W1, const float* __restrict__ b1,
    const float* __restrict__ W2, const float* __restrict__ b2,
    const float* __restrict__ W3, const float* __restrict__ b3,
    const float* __restrict__ W4, const float* __restrict__ b4,
    const float* __restrict__ W5, const float* __restrict__ b5,
    float* __restrict__ out, int N, int start)
{
    const int i = start + blockIdx.x * 256 + threadIdx.x;
    if (i >= N) return;
    const float* xr = x + (size_t)i * 11;
    float feats[41];
    for (int k = 0; k < 9; ++k) feats[k] = xr[k];
    for (int f = 0; f < 16; ++f) {
        const float ang = 6.283185f * (xr[9] * Bl[f] + xr[10] * Bl[16 + f]);
        float s, c; __sincosf(ang, &s, &c);
        feats[9 + f] = c; feats[25 + f] = s;
    }
    float h[16], gg[16];
    for (int j = 0; j < 16; ++j) h[j] = b1[j];
    for (int k = 0; k < 41; ++k)
        for (int j = 0; j < 16; ++j) h[j] = fmaf(feats[k], W1[k * 16 + j], h[j]);
    for (int j = 0; j < 16; ++j) h[j] = h[j] > 0.f ? h[j] : __expf(h[j]) - 1.f;
    for (int j = 0; j < 16; ++j) gg[j] = b2[j];
    for (int k = 0; k < 16; ++k)
        for (int j = 0; j < 16; ++j) gg[j] = fmaf(h[k], W2[k * 16 + j], gg[j]);
    for (int j = 0; j < 16; ++j) gg[j] = gg[j] > 0.f ? gg[j] : __expf(gg[j]) - 1.f;
    for (int j = 0; j < 16; ++j) h[j] = b3[j];
    for (int k = 0; k < 16; ++k)
        for (int j = 0; j < 16; ++j) h[j] = fmaf(gg[k], W3[k * 16 + j], h[j]);
    for (int j = 0; j < 16; ++j) h[j] = h[j] > 0.f ? h[j] : __expf(h[j]) - 1.f;
    for (int j = 0; j < 16; ++j) gg[j] = b4[j];
    for (int k = 0; k < 16; ++k)
        for (int j = 0; j < 16; ++j) gg[j] = fmaf(h[k], W4[k * 16 + j], gg[j]);
    for (int j = 0; j < 16; ++j) gg[j] = gg[j] > 0.f ? gg[j] : __expf(gg[j]) - 1.f;
    float o = b5[0];
    for (int j = 0; j < 16; ++j) o = fmaf(gg[j], W5[j], o);
    out[i] = o;
}

extern "C" void kernel_launch(void* const* d_in, const int* in_sizes, int n_in,
                              void* d_out, int out_size, void* d_ws, size_t ws_size,
                              hipStream_t stream) {
    const float* x  = (const float*)d_in[0];
    const float* Bl = (const float*)d_in[1];
    const float* W1 = (const float*)d_in[2];
    const float* b1 = (const float*)d_in[3];
    const float* W2 = (const float*)d_in[4];
    const float* b2 = (const float*)d_in[5];
    const float* W3 = (const float*)d_in[6];
    const float* b3 = (const float*)d_in[7];
    const float* W4 = (const float*)d_in[8];
    const float* b4 = (const float*)d_in[9];
    const float* W5 = (const float*)d_in[10];
    const float* b5 = (const float*)d_in[11];
    float* out = (float*)d_out;

    const int N = out_size;
    const int samples_per_block = 32 * NSB;        // 2 waves * 16*NSB = 1024
    const int NB = N / samples_per_block;
    const int rem = N - NB * samples_per_block;
    if (NB > 0)
        pixenc_mfma17<<<NB, 128, 0, stream>>>(x, Bl, W1, b1, W2, b2, W3, b3,
                                              W4, b4, W5, b5, out);
    if (rem > 0)
        pixenc_tail<<<(rem + 255) / 256, 256, 0, stream>>>(
            x, Bl, W1, b1, W2, b2, W3, b3, W4, b4, W5, b5, out, N,
            NB * samples_per_block);
}

// Round 20
// 118.644 us; speedup vs baseline: 1.0541x; 1.0541x over previous
//
#include <hip/hip_runtime.h>

typedef __fp16   cvt16x2 __attribute__((ext_vector_type(2)));
typedef _Float16 h2      __attribute__((ext_vector_type(2)));
typedef _Float16 half4_t __attribute__((ext_vector_type(4)));
typedef unsigned uint2v  __attribute__((ext_vector_type(2)));
typedef float    f32x4   __attribute__((ext_vector_type(4)));
typedef float    f32x4u  __attribute__((ext_vector_type(4), aligned(4)));

#define CH 16  // 64-sample chunks per wave; 128-thread block => 2048 samples
#define LOG2E 1.44269504f
#define LN2   0.69314718f

#if !__has_builtin(__builtin_elementwise_exp2)
extern "C" __device__ _Float16 __ocml_exp2_f16(_Float16);
#endif

__device__ __forceinline__ unsigned pk(float a, float b) {
    cvt16x2 h = __builtin_amdgcn_cvt_pkrtz(a, b);
    return __builtin_bit_cast(unsigned, h);
}
__device__ __forceinline__ half4_t mkfrag(unsigned lo, unsigned hi) {
    uint2v u; u[0] = lo; u[1] = hi;
    return __builtin_bit_cast(half4_t, u);
}

// Scaled-domain ELU (hardware v_exp_f16).
__device__ __forceinline__ unsigned elu_pk(float a, float b) {
    h2 v = __builtin_bit_cast(h2, __builtin_amdgcn_cvt_pkrtz(a, b));
    const h2 z   = {(_Float16)0.f, (_Float16)0.f};
    const h2 lg  = {(_Float16)LOG2E, (_Float16)LOG2E};
    const h2 mlg = {(_Float16)(-LOG2E), (_Float16)(-LOG2E)};
    h2 t = __builtin_elementwise_min(v, z);
#if __has_builtin(__builtin_elementwise_exp2)
    h2 ev = __builtin_elementwise_exp2(t);
#else
    h2 ev; ev[0] = __ocml_exp2_f16(t[0]); ev[1] = __ocml_exp2_f16(t[1]);
#endif
    h2 r = __builtin_elementwise_max(v, ev * lg + mlg);
    return __builtin_bit_cast(unsigned, r);
}

// R16 winner (rotated pipeline: BACK(c) || FRONT(c+1) via acc double-buffer)
// with CH=16 (halved per-block fixed cost) and b5 as SGPR scalar add.
__global__ __launch_bounds__(128, 4) void pixenc_mfma18(
    const float* __restrict__ x,
    const float* __restrict__ Bl,
    const float* __restrict__ W1, const float* __restrict__ b1,
    const float* __restrict__ W2, const float* __restrict__ b2,
    const float* __restrict__ W3, const float* __restrict__ b3,
    const float* __restrict__ W4, const float* __restrict__ b4,
    const float* __restrict__ W5, const float* __restrict__ b5,
    float* __restrict__ out)
{
    const int t    = threadIdx.x;
    const int lane = t & 63;
    const int w    = t >> 6;
    const int g    = lane >> 4;
    const int m    = lane & 15;

    const int coff = (g == 0) ? 7 : (g == 2) ? 3 : 0;   // 16B window start

    half4_t A1[3], A2, A3, A4;
    #pragma unroll
    for (int e = 0; e < 4; ++e) {
        const bool valid = (g == 1) | (g == 0 && e < 2) | (g == 2 && e >= 1);
        A1[0][e] = valid ? (_Float16)(W1[(coff + e) * 16 + m] * LOG2E)
                         : (_Float16)0.f;
        A1[1][e] = (_Float16)(W1[(9  + g * 4 + e) * 16 + m] * LOG2E);
        A1[2][e] = (_Float16)(W1[(25 + g * 4 + e) * 16 + m] * LOG2E);
        A2[e]    = (_Float16)W2[(g * 4 + e) * 16 + m];
        A3[e]    = (_Float16)W3[(g * 4 + e) * 16 + m];
        A4[e]    = (_Float16)W4[(g * 4 + e) * 16 + m];
    }
    const half4_t Az = (g == 0) ? mkfrag(pk(Bl[m], Bl[16 + m]), 0u)
                                : mkfrag(0u, 0u);
    const half4_t A5 = (m == 0)
        ? mkfrag(pk(W5[g * 4 + 0] * LN2, W5[g * 4 + 1] * LN2),
                 pk(W5[g * 4 + 2] * LN2, W5[g * 4 + 3] * LN2))
        : mkfrag(0u, 0u);
    f32x4 c1, c2, c3, c4;
    #pragma unroll
    for (int e = 0; e < 4; ++e) {
        const int r = g * 4 + e;
        c1[e] = b1[r] * LOG2E; c2[e] = b2[r] * LOG2E;
        c3[e] = b3[r] * LOG2E; c4[e] = b4[r] * LOG2E;
    }
    const f32x4 zero4 = {0.f, 0.f, 0.f, 0.f};
    const float b5v = b5[0];                     // uniform -> SGPR

    const int wavebase = blockIdx.x * (128 * CH) + w * (64 * CH);
    const float* aP = x + (size_t)(wavebase + m) * 11 + coff;
    float* outp = out + wavebase + m;

    // FRONT: z-MFMA + sincos + L1 chain for one chunk's 4 sub-batches.
    auto FRONT = [&](const unsigned* p01, const unsigned* p23, f32x4* acc) {
        f32x4 az[4];
        #pragma unroll
        for (int s = 0; s < 4; ++s)
            az[s] = __builtin_amdgcn_mfma_f32_16x16x16f16(
                        Az, mkfrag(p23[s], 0u), zero4, 0, 0, 0);
        #pragma unroll
        for (int s = 0; s < 4; ++s) {
            float cs[4], sn[4];
            #pragma unroll
            for (int e = 0; e < 4; ++e) {
                cs[e] = __builtin_amdgcn_cosf(az[s][e]);
                sn[e] = __builtin_amdgcn_sinf(az[s][e]);
            }
            const half4_t F0 = mkfrag(p01[s], p23[s]);
            const half4_t F1 = mkfrag(pk(cs[0], cs[1]), pk(cs[2], cs[3]));
            const half4_t F2 = mkfrag(pk(sn[0], sn[1]), pk(sn[2], sn[3]));
            f32x4 a = __builtin_amdgcn_mfma_f32_16x16x16f16(A1[0], F0, c1, 0, 0, 0);
            a = __builtin_amdgcn_mfma_f32_16x16x16f16(A1[1], F1, a, 0, 0, 0);
            a = __builtin_amdgcn_mfma_f32_16x16x16f16(A1[2], F2, a, 0, 0, 0);
            acc[s] = a;
        }
    };

    // BACK: elu+L2..L4+head+store for chunk c.
    auto BACK = [&](int c, f32x4* acc) {
        half4_t H[4];
        #pragma unroll
        for (int s = 0; s < 4; ++s)
            H[s] = mkfrag(elu_pk(acc[s][0], acc[s][1]), elu_pk(acc[s][2], acc[s][3]));
        #pragma unroll
        for (int s = 0; s < 4; ++s)
            acc[s] = __builtin_amdgcn_mfma_f32_16x16x16f16(A2, H[s], c2, 0, 0, 0);
        #pragma unroll
        for (int s = 0; s < 4; ++s)
            H[s] = mkfrag(elu_pk(acc[s][0], acc[s][1]), elu_pk(acc[s][2], acc[s][3]));
        #pragma unroll
        for (int s = 0; s < 4; ++s)
            acc[s] = __builtin_amdgcn_mfma_f32_16x16x16f16(A3, H[s], c3, 0, 0, 0);
        #pragma unroll
        for (int s = 0; s < 4; ++s)
            H[s] = mkfrag(elu_pk(acc[s][0], acc[s][1]), elu_pk(acc[s][2], acc[s][3]));
        #pragma unroll
        for (int s = 0; s < 4; ++s)
            acc[s] = __builtin_amdgcn_mfma_f32_16x16x16f16(A4, H[s], c4, 0, 0, 0);
        #pragma unroll
        for (int s = 0; s < 4; ++s)
            H[s] = mkfrag(elu_pk(acc[s][0], acc[s][1]), elu_pk(acc[s][2], acc[s][3]));
        #pragma unroll
        for (int s = 0; s < 4; ++s) {
            const f32x4 oh = __builtin_amdgcn_mfma_f32_16x16x16f16(
                                 A5, H[s], zero4, 0, 0, 0);
            if (g == 0) outp[c * 64 + s * 16] = oh[0] + b5v;
        }
    };

    // ---- prologue: load chunk 0, run FRONT(0) ----
    unsigned cp01[4], cp23[4];
    #pragma unroll
    for (int s = 0; s < 4; ++s) {
        const f32x4u v = *(const f32x4u*)(aP + s * 176);
        cp01[s] = pk(v[0], v[1]);
        cp23[s] = pk(v[2], v[3]);
    }
    f32x4 accbuf[2][4];                 // (c&1) is compile-time under unroll
    FRONT(cp01, cp23, accbuf[0]);

    #pragma unroll
    for (int c = 0; c < CH; ++c) {
        unsigned np01[4], np23[4];
        if (c + 1 < CH) {
            aP += 704;
            #pragma unroll
            for (int s = 0; s < 4; ++s) {
                const f32x4u v = *(const f32x4u*)(aP + s * 176);
                np01[s] = pk(v[0], v[1]);
                np23[s] = pk(v[2], v[3]);
            }
        }

        BACK(c, accbuf[c & 1]);                      // chunk c finish
        if (c + 1 < CH)
            FRONT(np01, np23, accbuf[(c + 1) & 1]);  // chunk c+1 start
    }
}

// Guarded scalar tail (only launched when N % 2048 != 0; never for N=8388608).
__global__ void pixenc_tail(
    const float* __restrict__ x, const float* __restrict__ Bl,
    const float* __restrict__ W1, const float* __restrict__ b1,
    const float* __restrict__ W2, const float* __restrict__ b2,
    const float* __restrict__ W3, const float* __restrict__ b3,
    const float* __restrict__ W4, const float* __restrict__ b4,
    const float* __restrict__ W5, const float* __restrict__ b5,
    float* __restrict__ out, int N, int start)
{
    const int i = start + blockIdx.x * 256 + threadIdx.x;
    if (i >= N) return;
    const float* xr = x + (size_t)i * 11;
    float feats[41];
    for (int k = 0; k < 9; ++k) feats[k] = xr[k];
    for (int f = 0; f < 16; ++f) {
        const float ang = 6.283185f * (xr[9] * Bl[f] + xr[10] * Bl[16 + f]);
        float s, c; __sincosf(ang, &s, &c);
        feats[9 + f] = c; feats[25 + f] = s;
    }
    float h[16], gg[16];
    for (int j = 0; j < 16; ++j) h[j] = b1[j];
    for (int k = 0; k < 41; ++k)
        for (int j = 0; j < 16; ++j) h[j] = fmaf(feats[k], W1[k * 16 + j], h[j]);
    for (int j = 0; j < 16; ++j) h[j] = h[j] > 0.f ? h[j] : __expf(h[j]) - 1.f;
    for (int j = 0; j < 16; ++j) gg[j] = b2[j];
    for (int k = 0; k < 16; ++k)
        for (int j = 0; j < 16; ++j) gg[j] = fmaf(h[k], W2[k * 16 + j], gg[j]);
    for (int j = 0; j < 16; ++j) gg[j] = gg[j] > 0.f ? gg[j] : __expf(gg[j]) - 1.f;
    for (int j = 0; j < 16; ++j) h[j] = b3[j];
    for (int k = 0; k < 16; ++k)
        for (int j = 0; j < 16; ++j) h[j] = fmaf(gg[k], W3[k * 16 + j], h[j]);
    for (int j = 0; j < 16; ++j) h[j] = h[j] > 0.f ? h[j] : __expf(h[j]) - 1.f;
    for (int j = 0; j < 16; ++j) gg[j] = b4[j];
    for (int k = 0; k < 16; ++k)
        for (int j = 0; j < 16; ++j) gg[j] = fmaf(h[k], W4[k * 16 + j], gg[j]);
    for (int j = 0; j < 16; ++j) gg[j] = gg[j] > 0.f ? gg[j] : __expf(gg[j]) - 1.f;
    float o = b5[0];
    for (int j = 0; j < 16; ++j) o = fmaf(gg[j], W5[j], o);
    out[i] = o;
}

extern "C" void kernel_launch(void* const* d_in, const int* in_sizes, int n_in,
                              void* d_out, int out_size, void* d_ws, size_t ws_size,
                              hipStream_t stream) {
    const float* x  = (const float*)d_in[0];
    const float* Bl = (const float*)d_in[1];
    const float* W1 = (const float*)d_in[2];
    const float* b1 = (const float*)d_in[3];
    const float* W2 = (const float*)d_in[4];
    const float* b2 = (const float*)d_in[5];
    const float* W3 = (const float*)d_in[6];
    const float* b3 = (const float*)d_in[7];
    const float* W4 = (const float*)d_in[8];
    const float* b4 = (const float*)d_in[9];
    const float* W5 = (const float*)d_in[10];
    const float* b5 = (const float*)d_in[11];
    float* out = (float*)d_out;

    const int N = out_size;
    const int samples_per_block = 128 * CH;        // 2048
    const int NB = N / samples_per_block;
    const int rem = N - NB * samples_per_block;
    if (NB > 0)
        pixenc_mfma18<<<NB, 128, 0, stream>>>(x, Bl, W1, b1, W2, b2, W3, b3,
                                              W4, b4, W5, b5, out);
    if (rem > 0)
        pixenc_tail<<<(rem + 255) / 256, 256, 0, stream>>>(
            x, Bl, W1, b1, W2, b2, W3, b3, W4, b4, W5, b5, out, N,
            NB * samples_per_block);
}